// Round 9
// baseline (462.510 us; speedup 1.0000x reference)
//
#include <hip/hip_runtime.h>

using bf16x8 = __attribute__((ext_vector_type(8))) __bf16;
using f32x16 = __attribute__((ext_vector_type(16))) float;
using f32x4  = __attribute__((ext_vector_type(4)))  float;

#define BB 4
#define DD 64
#define LL 4096

// Kernel 1: x[b,l,d] = sum_k pe[b,k,l]*W[d,k] + bias[d];
// xs = bf16(x * sqrt(log2e)/ls)  (log2-domain pre-scale);
// h = 0.5*sum(xs_rounded^2)  -> MFMA dot - hi - hj is directly the exp2 arg.
__global__ __launch_bounds__(256) void prep_kernel(
    const float* __restrict__ pe,   // [B][D][L]
    const float* __restrict__ W,    // [D][D] row-major (out,in)
    const float* __restrict__ bias, // [D]
    const float* __restrict__ ls,   // scalar
    __bf16* __restrict__ xs,        // [B][L][D]
    float* __restrict__ h)          // [B][L]
{
    __shared__ float pe_lds[DD][64];
    __shared__ float W_lds[DD * DD];
    __shared__ float hpart[4][64];

    const int tid = threadIdx.x;
    const int blk = blockIdx.x;        // 256 blocks
    const int b  = blk >> 6;
    const int l0 = (blk & 63) * 64;

    {
        const int l = tid & 63;
        const int kb = tid >> 6;
        #pragma unroll
        for (int it = 0; it < 16; ++it) {
            const int k = it * 4 + kb;
            pe_lds[k][l] = pe[((size_t)b * DD + k) * LL + l0 + l];
        }
    }
    #pragma unroll
    for (int it = 0; it < 16; ++it)
        W_lds[it * 256 + tid] = W[it * 256 + tid];
    __syncthreads();

    const int w = tid >> 6;    // wave owns d-range [w*16, w*16+16)
    const int l = tid & 63;    // lane owns one l
    const float SQRT_LOG2E = 1.2011224087864498f;  // sqrt(1/ln2)
    const float scale = SQRT_LOG2E / ls[0];

    float acc[16];
    #pragma unroll
    for (int i = 0; i < 16; ++i) acc[i] = bias[w * 16 + i];

    for (int k4 = 0; k4 < 16; ++k4) {
        const float p0 = pe_lds[k4 * 4 + 0][l];
        const float p1 = pe_lds[k4 * 4 + 1][l];
        const float p2 = pe_lds[k4 * 4 + 2][l];
        const float p3 = pe_lds[k4 * 4 + 3][l];
        #pragma unroll
        for (int i = 0; i < 16; ++i) {
            const float4 wv = *(const float4*)&W_lds[(w * 16 + i) * DD + k4 * 4];
            acc[i] += p0 * wv.x + p1 * wv.y + p2 * wv.z + p3 * wv.w;
        }
    }

    // bf16 round, h accumulated from the ROUNDED values (diagonal consistency)
    unsigned short out16[16];
    float hs = 0.0f;
    #pragma unroll
    for (int i = 0; i < 16; ++i) {
        const float xf = acc[i] * scale;
        const __bf16 bv = (__bf16)xf;
        const float xr = (float)bv;
        hs += xr * xr;
        out16[i] = __builtin_bit_cast(unsigned short, bv);
    }
    {
        __bf16* dst = xs + ((size_t)b * LL + l0 + l) * DD + w * 16;
        *(uint4*)dst       = *(const uint4*)&out16[0];
        *(uint4*)(dst + 8) = *(const uint4*)&out16[8];
    }
    hpart[w][l] = hs;
    __syncthreads();
    if (tid < 64) {
        const float s = hpart[0][tid] + hpart[1][tid] + hpart[2][tid] + hpart[3][tid];
        h[(size_t)b * LL + tid + l0] = 0.5f * s;
    }
}

// Kernel 2: fill-like streaming gram. Gram symmetry (C = C^T) lets us SWAP
// MFMA operands: operand1 <- column-set, operand2 <- row-set. Using the
// in-situ-verified mapping (operand1-set -> axis f(r,lg)=(r&3)+8*(r>>2)+4*lg,
// operand2-set -> axis lane&31), each lane then owns a FIXED output row
// (row = R0 + lane&31) and its 16 acc values sit at 4 groups of 4
// CONSECUTIVE columns -> dwordx4 NT stores (16 B/lane), no LDS, no barriers.
// Wave = 32 rows x 512 cols: row-fragments (bg) + row-h hoisted; 16-iter
// loop over 32-col tiles streams each lane's stores near-sequentially along
// its row, like the 6.8 TB/s fill. ~110 VGPR, 1024 blocks, 4 waves each.
__global__ __launch_bounds__(256) void gram_kernel(
    const __bf16* __restrict__ xs,  // [B][L][D]
    const float* __restrict__ h,    // [B][L]
    const float* __restrict__ osc,  // scalar
    float* __restrict__ out)        // [B][L][L]
{
    const int bid = blockIdx.x;       // 1024 = 4 * 32 * 8
    const int b  = bid >> 8;
    const int t  = bid & 255;
    const int rt = t >> 3;            // 32 row-tiles of 128
    const int cq = t & 7;             // 8 col-quads of 512

    const int tid  = threadIdx.x;
    const int wid  = tid >> 6;
    const int lane = tid & 63;
    const int lr = lane & 31, lg = lane >> 5;

    const int R0      = rt * 128 + wid * 32;   // wave's 32-row strip
    const int colbase = cq * 512;               // wave's 512-col range

    const __bf16* xsb = xs + (size_t)b * LL * DD;
    const float*  hb  = h + (size_t)b * LL;

    const float c  = osc[0];
    const float lc = __builtin_log2f(c);

    // Hoisted row-side state (fixed for the whole loop):
    // operand2 (bg) <- row-set; same (lane,slot)->k formula as operand1.
    bf16x8 bg[4];
    #pragma unroll
    for (int kk = 0; kk < 4; ++kk)
        bg[kk] = *(const bf16x8*)(xsb + (size_t)(R0 + lr) * DD + kk * 16 + lg * 8);

    const float hrow2 = hb[R0 + lr] - lc;   // h[row] - log2(outputscale)

    float* const orow = out + ((size_t)b * LL + R0 + lr) * LL;  // lane's row

    #pragma unroll 1
    for (int ct = 0; ct < 16; ++ct) {
        const int C0 = colbase + ct * 32;

        // operand1 (af) <- column-set (reloaded per tile; L2-hot, 16B/lane)
        bf16x8 af[4];
        #pragma unroll
        for (int kk = 0; kk < 4; ++kk)
            af[kk] = *(const bf16x8*)(xsb + (size_t)(C0 + lr) * DD + kk * 16 + lg * 8);

        f32x16 acc = (f32x16)(0.0f);
        #pragma unroll
        for (int kk = 0; kk < 4; ++kk)
            acc = __builtin_amdgcn_mfma_f32_32x32x16_bf16(af[kk], bg[kk], acc, 0, 0, 0);

        // acc[r] = dot(xs[C0 + f(r,lg)], xs[R0 + lr]) = out[R0+lr][C0+f(r,lg)]
        // f(r,lg) = (r&3) + 8*(r>>2) + 4*lg: per r-group g, 4 consecutive cols
        // at C0 + 8g + 4lg  -> one dwordx4 NT store per group.
        #pragma unroll
        for (int g = 0; g < 4; ++g) {
            const int cg = C0 + 8 * g + 4 * lg;
            const f32x4 hjv = *(const f32x4*)&hb[cg];
            f32x4 v;
            #pragma unroll
            for (int e = 0; e < 4; ++e) {
                float tt = acc[4 * g + e] - hrow2 - hjv[e];  // log2-scaled
                tt = fminf(tt, lc);                          // clamp + scale fold
                v[e] = __builtin_amdgcn_exp2f(tt);
            }
            __builtin_nontemporal_store(v, (f32x4*)(orow + cg));
        }
    }
}

extern "C" void kernel_launch(void* const* d_in, const int* in_sizes, int n_in,
                              void* d_out, int out_size, void* d_ws, size_t ws_size,
                              hipStream_t stream) {
    const float* pe   = (const float*)d_in[0];
    const float* W    = (const float*)d_in[1];
    const float* bias = (const float*)d_in[2];
    const float* ls   = (const float*)d_in[3];
    const float* osc  = (const float*)d_in[4];
    float* out = (float*)d_out;

    __bf16* xs = (__bf16*)d_ws;                                       // 2 MiB
    float*  h  = (float*)((char*)d_ws + (size_t)BB * LL * DD * 2);    // 64 KiB

    prep_kernel<<<256, 256, 0, stream>>>(pe, W, bias, ls, xs, h);
    gram_kernel<<<BB * 32 * 8, 256, 0, stream>>>(xs, h, osc, out);
}

// Round 10
// 81.633 us; speedup vs baseline: 5.6657x; 5.6657x over previous
//
#include <hip/hip_runtime.h>

using bf16x8 = __attribute__((ext_vector_type(8))) __bf16;
using f32x16 = __attribute__((ext_vector_type(16))) float;

#define BB 4
#define DD 64
#define LL 4096

// Kernel 1: x[b,l,d] = sum_k pe[b,k,l]*W[d,k] + bias[d];
// xs = bf16(x * sqrt(log2e)/ls)  (log2-domain pre-scale);
// h = 0.5*sum(xs_rounded^2)  -> MFMA dot - hi - hj is directly the exp2 arg.
__global__ __launch_bounds__(256) void prep_kernel(
    const float* __restrict__ pe,   // [B][D][L]
    const float* __restrict__ W,    // [D][D] row-major (out,in)
    const float* __restrict__ bias, // [D]
    const float* __restrict__ ls,   // scalar
    __bf16* __restrict__ xs,        // [B][L][D]
    float* __restrict__ h)          // [B][L]
{
    __shared__ float pe_lds[DD][64];
    __shared__ float W_lds[DD * DD];
    __shared__ float hpart[4][64];

    const int tid = threadIdx.x;
    const int blk = blockIdx.x;        // 256 blocks
    const int b  = blk >> 6;
    const int l0 = (blk & 63) * 64;

    {
        const int l = tid & 63;
        const int kb = tid >> 6;
        #pragma unroll
        for (int it = 0; it < 16; ++it) {
            const int k = it * 4 + kb;
            pe_lds[k][l] = pe[((size_t)b * DD + k) * LL + l0 + l];
        }
    }
    #pragma unroll
    for (int it = 0; it < 16; ++it)
        W_lds[it * 256 + tid] = W[it * 256 + tid];
    __syncthreads();

    const int w = tid >> 6;    // wave owns d-range [w*16, w*16+16)
    const int l = tid & 63;    // lane owns one l
    const float SQRT_LOG2E = 1.2011224087864498f;  // sqrt(1/ln2)
    const float scale = SQRT_LOG2E / ls[0];

    float acc[16];
    #pragma unroll
    for (int i = 0; i < 16; ++i) acc[i] = bias[w * 16 + i];

    for (int k4 = 0; k4 < 16; ++k4) {
        const float p0 = pe_lds[k4 * 4 + 0][l];
        const float p1 = pe_lds[k4 * 4 + 1][l];
        const float p2 = pe_lds[k4 * 4 + 2][l];
        const float p3 = pe_lds[k4 * 4 + 3][l];
        #pragma unroll
        for (int i = 0; i < 16; ++i) {
            const float4 wv = *(const float4*)&W_lds[(w * 16 + i) * DD + k4 * 4];
            acc[i] += p0 * wv.x + p1 * wv.y + p2 * wv.z + p3 * wv.w;
        }
    }

    // bf16 round, h accumulated from the ROUNDED values (diagonal consistency)
    unsigned short out16[16];
    float hs = 0.0f;
    #pragma unroll
    for (int i = 0; i < 16; ++i) {
        const float xf = acc[i] * scale;
        const __bf16 bv = (__bf16)xf;
        const float xr = (float)bv;
        hs += xr * xr;
        out16[i] = __builtin_bit_cast(unsigned short, bv);
    }
    {
        __bf16* dst = xs + ((size_t)b * LL + l0 + l) * DD + w * 16;
        *(uint4*)dst       = *(const uint4*)&out16[0];
        *(uint4*)(dst + 8) = *(const uint4*)&out16[8];
    }
    hpart[w][l] = hs;
    __syncthreads();
    if (tid < 64) {
        const float s = hpart[0][tid] + hpart[1][tid] + hpart[2][tid] + hpart[3][tid];
        h[(size_t)b * LL + tid + l0] = 0.5f * s;
    }
}

// Kernel 2: persistent row-stripe blocks. 256 blocks (1 per CU); each block
// owns a 64-row x 4096-col output stripe and walks 32 col-windows of 128.
// Each output row is written SEQUENTIALLY start-to-finish by the same wave
// (fill-style DRAM stream): store order r-outer/nt-inner gives 256B
// in-time-contiguous per row per iteration, advancing +512B per iteration.
// af/hi2 hoisted once per block; bg/hj double-buffered with NAMED buffers
// (no runtime indexing) and loaded BEFORE the previous window's stores in
// program order, so waitcnt never drains the store backlog. R4-proven
// elements kept: NT dword stores (128B full-line segments), independent
// MFMA chains, log2-domain epilogue, no barriers, no launch_bounds cap.
__global__ __launch_bounds__(256) void gram_kernel(
    const __bf16* __restrict__ xs,  // [B][L][D]
    const float* __restrict__ h,    // [B][L]
    const float* __restrict__ osc,  // scalar
    float* __restrict__ out)        // [B][L][L]
{
    const int bid = blockIdx.x;       // 256 = 4 batches * 64 row-stripes
    const int b  = bid >> 6;
    const int rt = bid & 63;

    const int tid  = threadIdx.x;
    const int wid  = tid >> 6;
    const int lane = tid & 63;
    const int lr = lane & 31, lg = lane >> 5;

    const int rows0 = rt * 64 + (wid >> 1) * 32;   // wave's 32-row strip
    const int colw  = (wid & 1) * 64;              // wave's 64-col half of each 128-col window

    const __bf16* xsb = xs + (size_t)b * LL * DD;
    const float*  hb  = h + (size_t)b * LL;

    const float c  = osc[0];
    const float lc = __builtin_log2f(c);

    // Hoisted row-side state (whole block lifetime).
    // A and B fragments use the IDENTICAL (lane,slot)->k mapping: any HW
    // k-permutation preserves the Gram dot product.
    bf16x8 af[4];
    #pragma unroll
    for (int kk = 0; kk < 4; ++kk)
        af[kk] = *(const bf16x8*)(xsb + (size_t)(rows0 + lr) * DD + kk * 16 + lg * 8);

    // C/D layout (verified): col = lane&31, row = (r&3)+8*(r>>2)+4*(lane>>5)
    float hi2[16];
    #pragma unroll
    for (int r = 0; r < 16; ++r)
        hi2[r] = hb[rows0 + (r & 3) + 8 * (r >> 2) + 4 * lg] - lc;

    float* const obase = out + ((size_t)b * LL + rows0 + 4 * lg) * LL;

    bf16x8 bgA[2][4], bgB[2][4];
    float  hjA[2], hjB[2];

#define LOADBG(BG, HJ, CT)                                                     \
    {                                                                          \
        const int C0 = (CT) * 128 + colw;                                      \
        _Pragma("unroll")                                                      \
        for (int nt = 0; nt < 2; ++nt) {                                       \
            _Pragma("unroll")                                                  \
            for (int kk = 0; kk < 4; ++kk)                                     \
                BG[nt][kk] = *(const bf16x8*)(xsb +                            \
                    (size_t)(C0 + nt * 32 + lr) * DD + kk * 16 + lg * 8);      \
            HJ[nt] = hb[C0 + nt * 32 + lr];                                    \
        }                                                                      \
    }

#define CS(BG, HJ, CT)                                                         \
    {                                                                          \
        f32x16 acc[2];                                                         \
        acc[0] = (f32x16)(0.0f);                                               \
        acc[1] = (f32x16)(0.0f);                                               \
        _Pragma("unroll")                                                      \
        for (int kk = 0; kk < 4; ++kk) {                                       \
            acc[0] = __builtin_amdgcn_mfma_f32_32x32x16_bf16(af[kk], BG[0][kk], acc[0], 0, 0, 0); \
            acc[1] = __builtin_amdgcn_mfma_f32_32x32x16_bf16(af[kk], BG[1][kk], acc[1], 0, 0, 0); \
        }                                                                      \
        const int C0 = (CT) * 128 + colw;                                      \
        _Pragma("unroll")                                                      \
        for (int r = 0; r < 16; ++r) {                                         \
            const size_t ro = (size_t)((r & 3) + 8 * (r >> 2)) * LL;           \
            _Pragma("unroll")                                                  \
            for (int nt = 0; nt < 2; ++nt) {                                   \
                float tt = acc[nt][r] - hi2[r] - HJ[nt];                       \
                tt = fminf(tt, lc);                                            \
                __builtin_nontemporal_store(__builtin_amdgcn_exp2f(tt),        \
                                            &obase[ro + C0 + nt * 32 + lr]);   \
            }                                                                  \
        }                                                                      \
    }

    LOADBG(bgA, hjA, 0)
    #pragma unroll 1
    for (int ct = 0; ct < 32; ct += 2) {
        LOADBG(bgB, hjB, ct + 1)   // in flight under window ct's stores
        CS(bgA, hjA, ct)
        if (ct + 2 < 32)
            LOADBG(bgA, hjA, ct + 2)
        CS(bgB, hjB, ct + 1)
    }

#undef LOADBG
#undef CS
}

extern "C" void kernel_launch(void* const* d_in, const int* in_sizes, int n_in,
                              void* d_out, int out_size, void* d_ws, size_t ws_size,
                              hipStream_t stream) {
    const float* pe   = (const float*)d_in[0];
    const float* W    = (const float*)d_in[1];
    const float* bias = (const float*)d_in[2];
    const float* ls   = (const float*)d_in[3];
    const float* osc  = (const float*)d_in[4];
    float* out = (float*)d_out;

    __bf16* xs = (__bf16*)d_ws;                                       // 2 MiB
    float*  h  = (float*)((char*)d_ws + (size_t)BB * LL * DD * 2);    // 64 KiB

    prep_kernel<<<256, 256, 0, stream>>>(pe, W, bias, ls, xs, h);
    gram_kernel<<<BB * 64, 256, 0, stream>>>(xs, h, osc, out);
}

// Round 11
// 61.285 us; speedup vs baseline: 7.5469x; 1.3320x over previous
//
#include <hip/hip_runtime.h>

using bf16x8 = __attribute__((ext_vector_type(8))) __bf16;
using f32x16 = __attribute__((ext_vector_type(16))) float;

#define BB 4
#define DD 64
#define LL 4096

// Kernel 1: x[b,l,d] = sum_k pe[b,k,l]*W[d,k] + bias[d];
// xs = bf16(x * sqrt(log2e)/ls)  (log2-domain pre-scale);
// h = 0.5*sum(xs_rounded^2)  -> MFMA dot - hi - hj is directly the exp2 arg.
__global__ __launch_bounds__(256) void prep_kernel(
    const float* __restrict__ pe,   // [B][D][L]
    const float* __restrict__ W,    // [D][D] row-major (out,in)
    const float* __restrict__ bias, // [D]
    const float* __restrict__ ls,   // scalar
    __bf16* __restrict__ xs,        // [B][L][D]
    float* __restrict__ h)          // [B][L]
{
    __shared__ float pe_lds[DD][64];
    __shared__ float W_lds[DD * DD];
    __shared__ float hpart[4][64];

    const int tid = threadIdx.x;
    const int blk = blockIdx.x;        // 256 blocks
    const int b  = blk >> 6;
    const int l0 = (blk & 63) * 64;

    {
        const int l = tid & 63;
        const int kb = tid >> 6;
        #pragma unroll
        for (int it = 0; it < 16; ++it) {
            const int k = it * 4 + kb;
            pe_lds[k][l] = pe[((size_t)b * DD + k) * LL + l0 + l];
        }
    }
    #pragma unroll
    for (int it = 0; it < 16; ++it)
        W_lds[it * 256 + tid] = W[it * 256 + tid];
    __syncthreads();

    const int w = tid >> 6;    // wave owns d-range [w*16, w*16+16)
    const int l = tid & 63;    // lane owns one l
    const float SQRT_LOG2E = 1.2011224087864498f;  // sqrt(1/ln2)
    const float scale = SQRT_LOG2E / ls[0];

    float acc[16];
    #pragma unroll
    for (int i = 0; i < 16; ++i) acc[i] = bias[w * 16 + i];

    for (int k4 = 0; k4 < 16; ++k4) {
        const float p0 = pe_lds[k4 * 4 + 0][l];
        const float p1 = pe_lds[k4 * 4 + 1][l];
        const float p2 = pe_lds[k4 * 4 + 2][l];
        const float p3 = pe_lds[k4 * 4 + 3][l];
        #pragma unroll
        for (int i = 0; i < 16; ++i) {
            const float4 wv = *(const float4*)&W_lds[(w * 16 + i) * DD + k4 * 4];
            acc[i] += p0 * wv.x + p1 * wv.y + p2 * wv.z + p3 * wv.w;
        }
    }

    // bf16 round, h accumulated from the ROUNDED values (diagonal consistency)
    unsigned short out16[16];
    float hs = 0.0f;
    #pragma unroll
    for (int i = 0; i < 16; ++i) {
        const float xf = acc[i] * scale;
        const __bf16 bv = (__bf16)xf;
        const float xr = (float)bv;
        hs += xr * xr;
        out16[i] = __builtin_bit_cast(unsigned short, bv);
    }
    {
        __bf16* dst = xs + ((size_t)b * LL + l0 + l) * DD + w * 16;
        *(uint4*)dst       = *(const uint4*)&out16[0];
        *(uint4*)(dst + 8) = *(const uint4*)&out16[8];
    }
    hpart[w][l] = hs;
    __syncthreads();
    if (tid < 64) {
        const float s = hpart[0][tid] + hpart[1][tid] + hpart[2][tid] + hpart[3][tid];
        h[(size_t)b * LL + tid + l0] = 0.5f * s;
    }
}

// Kernel 2: measured-best configuration (R4, 61.3us): 4096 blocks, 128x128
// tile, 4 waves, 64x64 per wave, all fragments upfront, no launch_bounds
// cap, NT stores (keep the dead-on-arrival 256MB output stream from
// evicting the 2MB xs set out of L2), log2-domain epilogue with
// lc = log2(outputscale) folded into the clamp.
__global__ __launch_bounds__(256) void gram_kernel(
    const __bf16* __restrict__ xs,  // [B][L][D]
    const float* __restrict__ h,    // [B][L]
    const float* __restrict__ osc,  // scalar
    float* __restrict__ out)        // [B][L][L]
{
    const int bid = blockIdx.x;       // 4096 = 4 * 32 * 32
    const int b  = bid >> 10;
    const int t  = bid & 1023;
    const int ti = t >> 5, tj = t & 31;

    const int tid  = threadIdx.x;
    const int wid  = tid >> 6;
    const int lane = tid & 63;
    const int lr = lane & 31, lg = lane >> 5;

    const int rows0 = ti * 128 + (wid >> 1) * 64;
    const int cols0 = tj * 128 + (wid & 1) * 64;

    const __bf16* xsb = xs + (size_t)b * LL * DD;
    const float*  hb  = h + (size_t)b * LL;

    // A and B fragments use the IDENTICAL (lane,slot)->k mapping: any HW
    // k-permutation preserves the Gram dot product.
    bf16x8 af[2][4], bg[2][4];
    #pragma unroll
    for (int mt = 0; mt < 2; ++mt)
        #pragma unroll
        for (int kk = 0; kk < 4; ++kk)
            af[mt][kk] = *(const bf16x8*)(xsb + (size_t)(rows0 + mt * 32 + lr) * DD + kk * 16 + lg * 8);
    #pragma unroll
    for (int nt = 0; nt < 2; ++nt)
        #pragma unroll
        for (int kk = 0; kk < 4; ++kk)
            bg[nt][kk] = *(const bf16x8*)(xsb + (size_t)(cols0 + nt * 32 + lr) * DD + kk * 16 + lg * 8);

    f32x16 acc[2][2];
    #pragma unroll
    for (int mt = 0; mt < 2; ++mt)
        #pragma unroll
        for (int nt = 0; nt < 2; ++nt)
            acc[mt][nt] = (f32x16)(0.0f);

    #pragma unroll
    for (int kk = 0; kk < 4; ++kk)
        #pragma unroll
        for (int mt = 0; mt < 2; ++mt)
            #pragma unroll
            for (int nt = 0; nt < 2; ++nt)
                acc[mt][nt] = __builtin_amdgcn_mfma_f32_32x32x16_bf16(
                    af[mt][kk], bg[nt][kk], acc[mt][nt], 0, 0, 0);

    const float c  = osc[0];
    const float lc = __builtin_log2f(c);

    #pragma unroll
    for (int mt = 0; mt < 2; ++mt) {
        // C/D layout (verified): col = lane&31, row = (r&3)+8*(r>>2)+4*(lane>>5)
        float hi2[16];
        #pragma unroll
        for (int r = 0; r < 16; ++r)
            hi2[r] = hb[rows0 + mt * 32 + (r & 3) + 8 * (r >> 2) + 4 * lg] - lc;
        #pragma unroll
        for (int nt = 0; nt < 2; ++nt) {
            const int col = cols0 + nt * 32 + lr;
            const float hj = hb[col];
            float* op = out + ((size_t)b * LL + rows0 + mt * 32 + 4 * lg) * LL + col;
            #pragma unroll
            for (int r = 0; r < 16; ++r) {
                float tt = acc[mt][nt][r] - hi2[r] - hj;  // log2-scaled
                tt = fminf(tt, lc);                       // clamp + outputscale
                const int rowoff = (r & 3) + 8 * (r >> 2);
                __builtin_nontemporal_store(__builtin_amdgcn_exp2f(tt),
                                            &op[(size_t)rowoff * LL]);
            }
        }
    }
}

extern "C" void kernel_launch(void* const* d_in, const int* in_sizes, int n_in,
                              void* d_out, int out_size, void* d_ws, size_t ws_size,
                              hipStream_t stream) {
    const float* pe   = (const float*)d_in[0];
    const float* W    = (const float*)d_in[1];
    const float* bias = (const float*)d_in[2];
    const float* ls   = (const float*)d_in[3];
    const float* osc  = (const float*)d_in[4];
    float* out = (float*)d_out;

    __bf16* xs = (__bf16*)d_ws;                                       // 2 MiB
    float*  h  = (float*)((char*)d_ws + (size_t)BB * LL * DD * 2);    // 64 KiB

    prep_kernel<<<256, 256, 0, stream>>>(pe, W, bias, ls, xs, h);
    gram_kernel<<<BB * 32 * 32, 256, 0, stream>>>(xs, h, osc, out);
}